// Round 3
// baseline (76011.023 us; speedup 1.0000x reference)
//
#include <hip/hip_runtime.h>

constexpr int BB = 64, TT = 512, DD = 512, HH = 512;
constexpr int GG = 4 * HH;         // 2048 gate cols
constexpr int KK = DD + HH;        // 1024 fused K
constexpr int NBLK = 256, NTHR = 512;

// ws: WT[GG][KK] f32 (8MB) | hbuf[2][BB*HH] f32 (256KB) | cnt (4B)

__global__ void prep_kernel(const float* __restrict__ Wx,   // [DD][GG]
                            const float* __restrict__ Wr,   // [HH][GG]
                            const float* __restrict__ init_h,
                            float* __restrict__ WT,
                            float* __restrict__ hbuf0,
                            unsigned* __restrict__ cnt) {
    int idx = blockIdx.x * blockDim.x + threadIdx.x;
    if (idx < GG * KK) {
        int g = idx >> 10;
        int k = idx & (KK - 1);
        WT[idx] = (k < DD) ? Wx[(size_t)k * GG + g] : Wr[(size_t)(k - DD) * GG + g];
    }
    if (idx < BB * HH) hbuf0[idx] = init_h[idx];
    if (idx == 0) *cnt = 0u;
}

__device__ __forceinline__ float dot16(float4 a0, float4 a1, float4 a2, float4 a3,
                                       float4 w0, float4 w1, float4 w2, float4 w3) {
    float s0 = 0.f, s1 = 0.f, s2 = 0.f, s3 = 0.f;
    s0 = fmaf(a0.x, w0.x, s0); s1 = fmaf(a0.y, w0.y, s1);
    s2 = fmaf(a0.z, w0.z, s2); s3 = fmaf(a0.w, w0.w, s3);
    s0 = fmaf(a1.x, w1.x, s0); s1 = fmaf(a1.y, w1.y, s1);
    s2 = fmaf(a1.z, w1.z, s2); s3 = fmaf(a1.w, w1.w, s3);
    s0 = fmaf(a2.x, w2.x, s0); s1 = fmaf(a2.y, w2.y, s1);
    s2 = fmaf(a2.z, w2.z, s2); s3 = fmaf(a2.w, w2.w, s3);
    s0 = fmaf(a3.x, w3.x, s0); s1 = fmaf(a3.y, w3.y, s1);
    s2 = fmaf(a3.z, w3.z, s2); s3 = fmaf(a3.w, w3.w, s3);
    return (s0 + s1) + (s2 + s3);
}

__global__ void __launch_bounds__(NTHR, 2)
lstm_kernel(const float* __restrict__ x,      // [B,T,D]
            const float* __restrict__ WT,     // [GG][KK]
            const float* __restrict__ bias,   // [GG]
            const int*   __restrict__ mask,   // [B,T]
            const float* __restrict__ init_h,
            const float* __restrict__ init_c,
            float*       hbuf,                // [2][B*H]
            unsigned*    cnt,
            float* __restrict__ out)          // outputs | h_f | c_f
{
    const int tid  = threadIdx.x;
    const int bid  = blockIdx.x;
    const int slot = tid >> 6;        // 0..7 : gate-col slot
    const int l6   = tid & 63;
    const int bl   = l6 >> 5;         // 0/1 : batch parity lane
    const int kg   = l6 & 31;         // 0..31 : k-group (16 k each per half)
    const int gate = slot >> 1;
    const int jj   = slot & 1;
    const int j0   = bid * 2;
    const int g    = gate * HH + j0 + jj;     // global gate column

    // ---- persistent weights: 32 f32 in VGPRs, loaded once ----
    const float4* wrow = reinterpret_cast<const float4*>(WT + (size_t)g * KK);
    const int k4 = kg * 4;                    // float4 idx of k = kg*16
    const float4 wx0 = wrow[k4 + 0], wx1 = wrow[k4 + 1],
                 wx2 = wrow[k4 + 2], wx3 = wrow[k4 + 3];
    const float4 wh0 = wrow[128 + k4 + 0], wh1 = wrow[128 + k4 + 1],
                 wh2 = wrow[128 + k4 + 2], wh3 = wrow[128 + k4 + 3];
    const float bz = bias[g];

    // ---- update-phase mapping (tid < 128): one (b, j) element ----
    const int ub = tid >> 1;          // 0..63
    const int uj = tid & 1;           // 0..1
    float c_reg = 0.f, h_reg = 0.f, po_reg = 0.f;
    if (tid < 128) {
        c_reg = init_c[ub * HH + j0 + uj];
        h_reg = init_h[ub * HH + j0 + uj];
    }

    __shared__ float z_lds[64][9];    // [b][slot], padded

    const size_t OUT_HF = (size_t)BB * TT * HH;
    const size_t OUT_CF = OUT_HF + (size_t)BB * HH;

    for (int t = 0; t < TT; ++t) {
        // ---- x-phase: xz[b] partials (no h dependence; overlaps barrier) ----
        float xz[32];
        #pragma unroll
        for (int it = 0; it < 32; ++it) {
            const float4* xa = reinterpret_cast<const float4*>(
                x + ((size_t)(2 * it + bl) * TT + t) * DD + kg * 16);
            xz[it] = dot16(xa[0], xa[1], xa[2], xa[3], wx0, wx1, wx2, wx3);
        }

        // ---- wait: h[t] produced by all blocks at step t-1 ----
        if (t > 0) {
            if (tid == 0) {
                const unsigned target = (unsigned)t * NBLK;
                while (__hip_atomic_load(cnt, __ATOMIC_RELAXED,
                                         __HIP_MEMORY_SCOPE_AGENT) < target)
                    __builtin_amdgcn_s_sleep(1);
            }
            __syncthreads();
            __builtin_amdgcn_fence(__ATOMIC_ACQUIRE, "agent");
        }

        const float* cur = hbuf + (size_t)(t & 1) * (BB * HH);
        float*       nxt = hbuf + (size_t)((t + 1) & 1) * (BB * HH);

        // ---- h-phase + in-wave k-reduction ----
        #pragma unroll
        for (int it = 0; it < 32; ++it) {
            const int b = 2 * it + bl;
            const float4* ha = reinterpret_cast<const float4*>(
                cur + (size_t)b * HH + kg * 16);
            float s = xz[it] + dot16(ha[0], ha[1], ha[2], ha[3], wh0, wh1, wh2, wh3);
            s += __shfl_xor(s, 1);
            s += __shfl_xor(s, 2);
            s += __shfl_xor(s, 4);
            s += __shfl_xor(s, 8);
            s += __shfl_xor(s, 16);
            if (kg == 0) z_lds[b][slot] = s + bz;
        }
        __syncthreads();

        // ---- gate nonlinearities + state update (Keras order i,f,g,o) ----
        if (tid < 128) {
            float zi = z_lds[ub][0 + uj];
            float zf = z_lds[ub][2 + uj];
            float zg = z_lds[ub][4 + uj];
            float zo = z_lds[ub][6 + uj];

            float ig = 1.f / (1.f + expf(-zi));
            float fg = 1.f / (1.f + expf(-zf));
            float gg = tanhf(zg);
            float og = 1.f / (1.f + expf(-zo));

            float c_new = fg * c_reg + ig * gg;
            float h_new = og * tanhf(c_new);

            bool m = (mask[ub * TT + t] != 0);
            float ov = m ? h_new : po_reg;
            float h2 = m ? h_new : h_reg;
            float c2 = m ? c_new : c_reg;

            out[((size_t)ub * TT + t) * HH + j0 + uj] = ov;
            nxt[ub * HH + j0 + uj] = h2;

            c_reg = c2; h_reg = h2; po_reg = ov;
            __threadfence();          // release h stores to device scope
        }
        __syncthreads();              // all block stores done before arrive

        // ---- arrive: generation t+1 ----
        if (tid == 0)
            __hip_atomic_fetch_add(cnt, 1u, __ATOMIC_RELAXED,
                                   __HIP_MEMORY_SCOPE_AGENT);
    }

    if (tid < 128) {
        out[OUT_HF + (size_t)ub * HH + j0 + uj] = h_reg;
        out[OUT_CF + (size_t)ub * HH + j0 + uj] = c_reg;
    }
}

extern "C" void kernel_launch(void* const* d_in, const int* in_sizes, int n_in,
                              void* d_out, int out_size, void* d_ws, size_t ws_size,
                              hipStream_t stream) {
    const float* x      = (const float*)d_in[0];
    const float* init_h = (const float*)d_in[1];
    const float* init_c = (const float*)d_in[2];
    const float* Wx     = (const float*)d_in[3];
    const float* Wr     = (const float*)d_in[4];
    const float* bias   = (const float*)d_in[5];
    const int*   mask   = (const int*)d_in[6];
    float* out  = (float*)d_out;

    float*    WT   = (float*)d_ws;                     // 8 MB
    float*    hbuf = WT + (size_t)GG * KK;             // 256 KB
    unsigned* cnt  = (unsigned*)(hbuf + 2 * BB * HH);  // 4 B

    prep_kernel<<<(GG * KK + 255) / 256, 256, 0, stream>>>(Wx, Wr, init_h, WT,
                                                           hbuf, cnt);

    void* args[] = { (void*)&x, (void*)&WT, (void*)&bias, (void*)&mask,
                     (void*)&init_h, (void*)&init_c, (void*)&hbuf,
                     (void*)&cnt, (void*)&out };
    (void)hipLaunchCooperativeKernel((const void*)lstm_kernel, dim3(NBLK),
                                     dim3(NTHR), args, 0, stream);
}

// Round 4
// 51267.157 us; speedup vs baseline: 1.4826x; 1.4826x over previous
//
#include <hip/hip_runtime.h>

constexpr int BB = 64, TT = 512, DD = 512, HH = 512;
constexpr int GG = 4 * HH;         // 2048 gate cols
constexpr int KK = DD + HH;        // 1024 fused K
constexpr int NBLK = 256, NTHR = 512;
constexpr int SMEM_FLOATS = BB * HH + 64 * 9;   // h_lds + z_lds = 133,376 B

// ws: WT[GG][KK] f32 (8MB) | hbuf[2][BB*HH] (256KB) | flags[NBLK] (1KB)

__global__ void prep_kernel(const float* __restrict__ Wx,   // [DD][GG]
                            const float* __restrict__ Wr,   // [HH][GG]
                            const float* __restrict__ init_h,
                            float* __restrict__ WT,
                            float* __restrict__ hbuf0,
                            unsigned* __restrict__ flags) {
    int idx = blockIdx.x * blockDim.x + threadIdx.x;
    if (idx < GG * KK) {
        int g = idx >> 10;
        int p = idx & (KK - 1);
        float v;
        if (p < DD) {
            v = Wx[(size_t)p * GG + g];          // x-half: identity k order
        } else {
            // h-half: lane kg owns k = 4*kg + 128*j + c  (4-way-bank LDS reads)
            int q = p - DD;
            int kg = q >> 4, j = (q >> 2) & 3, c = q & 3;
            int k = 4 * kg + 128 * j + c;
            v = Wr[(size_t)k * GG + g];
        }
        WT[idx] = v;
    }
    if (idx < BB * HH) hbuf0[idx] = init_h[idx];
    if (idx < NBLK) flags[idx] = 0u;
}

__device__ __forceinline__ float dot16(float4 a0, float4 a1, float4 a2, float4 a3,
                                       float4 w0, float4 w1, float4 w2, float4 w3) {
    float s0 = 0.f, s1 = 0.f, s2 = 0.f, s3 = 0.f;
    s0 = fmaf(a0.x, w0.x, s0); s1 = fmaf(a0.y, w0.y, s1);
    s2 = fmaf(a0.z, w0.z, s2); s3 = fmaf(a0.w, w0.w, s3);
    s0 = fmaf(a1.x, w1.x, s0); s1 = fmaf(a1.y, w1.y, s1);
    s2 = fmaf(a1.z, w1.z, s2); s3 = fmaf(a1.w, w1.w, s3);
    s0 = fmaf(a2.x, w2.x, s0); s1 = fmaf(a2.y, w2.y, s1);
    s2 = fmaf(a2.z, w2.z, s2); s3 = fmaf(a2.w, w2.w, s3);
    s0 = fmaf(a3.x, w3.x, s0); s1 = fmaf(a3.y, w3.y, s1);
    s2 = fmaf(a3.z, w3.z, s2); s3 = fmaf(a3.w, w3.w, s3);
    return (s0 + s1) + (s2 + s3);
}

__global__ void __launch_bounds__(NTHR, 2)
lstm_kernel(const float* __restrict__ x,      // [B,T,D]
            const float* __restrict__ WT,     // [GG][KK] (h-half k-permuted)
            const float* __restrict__ bias,   // [GG]
            const int*   __restrict__ mask,   // [B,T]
            const float* __restrict__ init_h,
            const float* __restrict__ init_c,
            float*       hbuf,                // [2][B*H], sc1-only traffic
            unsigned*    flags,               // [NBLK], sc1-only traffic
            float* __restrict__ out)          // outputs | h_f | c_f
{
    extern __shared__ float smem[];
    float* h_lds = smem;                 // [64][512] f32 = 128 KB
    float* z_l   = smem + BB * HH;       // [64][9] padded

    const int tid  = threadIdx.x;
    const int bid  = blockIdx.x;
    const int slot = tid >> 6;           // 0..7 : gate-col slot
    const int l6   = tid & 63;
    const int bl   = l6 >> 5;            // 0/1 batch parity
    const int kg   = l6 & 31;            // k-group
    const int gate = slot >> 1;
    const int jj   = slot & 1;
    // XCD-friendly column relabeling: blocks with bid%8==x (same XCD under
    // round-robin dispatch) own contiguous j -> full out/h cache lines per L2.
    const int j0   = 2 * ((bid & 7) * 32 + (bid >> 3));
    const int g    = gate * HH + j0 + jj;

    // ---- persistent weights: 32 f32 in VGPRs ----
    const float4* wrow = reinterpret_cast<const float4*>(WT + (size_t)g * KK);
    const int k4 = kg * 4;
    const float4 wx0 = wrow[k4 + 0], wx1 = wrow[k4 + 1],
                 wx2 = wrow[k4 + 2], wx3 = wrow[k4 + 3];
    const float4 wh0 = wrow[128 + k4 + 0], wh1 = wrow[128 + k4 + 1],
                 wh2 = wrow[128 + k4 + 2], wh3 = wrow[128 + k4 + 3];
    const float bz = bias[g];

    // ---- update-phase mapping (tid < 128) ----
    const int ub = tid >> 1;
    const int uj = tid & 1;
    float c_reg = 0.f, h_reg = 0.f, po_reg = 0.f;
    if (tid < 128) {
        c_reg = init_c[ub * HH + j0 + uj];
        h_reg = init_h[ub * HH + j0 + uj];
    }

    const size_t OUT_HF = (size_t)BB * TT * HH;
    const size_t OUT_CF = OUT_HF + (size_t)BB * HH;
    const int stage_base = (tid >> 6) * 4096 + (tid & 63);

    for (int t = 0; t < TT; ++t) {
        // ---- x-phase (no h dep; overlaps other blocks' tail/arrive) ----
        float xz[32];
        #pragma unroll
        for (int it = 0; it < 32; ++it) {
            const float4* xa = reinterpret_cast<const float4*>(
                x + ((size_t)(2 * it + bl) * TT + t) * DD + kg * 16);
            xz[it] = dot16(xa[0], xa[1], xa[2], xa[3], wx0, wx1, wx2, wx3);
        }

        // ---- wait: all flags >= t (wave 0 polls; distinct addrs, no RMW) ----
        if (tid < 64) {
            const unsigned tgt = (unsigned)t;
            for (;;) {
                bool ok = true;
                #pragma unroll
                for (int q = 0; q < 4; ++q) {
                    unsigned v = __hip_atomic_load(flags + q * 64 + tid,
                                                   __ATOMIC_RELAXED,
                                                   __HIP_MEMORY_SCOPE_AGENT);
                    ok &= (v >= tgt);
                }
                if (__all(ok)) break;
                __builtin_amdgcn_s_sleep(2);
            }
        }
        __syncthreads();

        const float* cur = hbuf + (size_t)(t & 1) * (BB * HH);
        float*       nxt = hbuf + (size_t)((t + 1) & 1) * (BB * HH);

        // ---- stage h -> LDS (coalesced sc1 loads, conflict-free ds_write) ----
        #pragma unroll 8
        for (int i = 0; i < 64; ++i) {
            int e = stage_base + i * 64;
            h_lds[e] = __hip_atomic_load(cur + e, __ATOMIC_RELAXED,
                                         __HIP_MEMORY_SCOPE_AGENT);
        }
        __syncthreads();

        // ---- h-phase from LDS (k-permuted: 4-way banks) + k-reduction ----
        #pragma unroll
        for (int it = 0; it < 32; ++it) {
            const int b = 2 * it + bl;
            const float4* hrow = reinterpret_cast<const float4*>(h_lds + b * HH);
            float4 h0 = hrow[kg], h1 = hrow[kg + 32],
                   h2 = hrow[kg + 64], h3 = hrow[kg + 96];
            float s = xz[it] + dot16(h0, h1, h2, h3, wh0, wh1, wh2, wh3);
            s += __shfl_xor(s, 1);
            s += __shfl_xor(s, 2);
            s += __shfl_xor(s, 4);
            s += __shfl_xor(s, 8);
            s += __shfl_xor(s, 16);
            if (kg == 0) z_l[b * 9 + slot] = s + bz;
        }
        __syncthreads();

        // ---- gate nonlinearities + state update (Keras order i,f,g,o) ----
        if (tid < 128) {
            float zi = z_l[ub * 9 + 0 + uj];
            float zf = z_l[ub * 9 + 2 + uj];
            float zg = z_l[ub * 9 + 4 + uj];
            float zo = z_l[ub * 9 + 6 + uj];

            float ig = 1.f / (1.f + expf(-zi));
            float fg = 1.f / (1.f + expf(-zf));
            float gg = tanhf(zg);
            float og = 1.f / (1.f + expf(-zo));

            float c_new = fg * c_reg + ig * gg;
            float h_new = og * tanhf(c_new);

            bool m = (mask[ub * TT + t] != 0);
            float ov = m ? h_new : po_reg;
            float h2 = m ? h_new : h_reg;
            float c2 = m ? c_new : c_reg;

            out[((size_t)ub * TT + t) * HH + j0 + uj] = ov;     // normal store
            __hip_atomic_store(nxt + ub * HH + j0 + uj, h2,     // sc1 store
                               __ATOMIC_RELAXED, __HIP_MEMORY_SCOPE_AGENT);

            c_reg = c2; h_reg = h2; po_reg = ov;
        }
        // __syncthreads drains vmcnt before s_barrier -> h-stores are at the
        // coherence point before the flag store below issues. No fences.
        __syncthreads();

        if (tid == 0)
            __hip_atomic_store(flags + bid, (unsigned)(t + 1),
                               __ATOMIC_RELAXED, __HIP_MEMORY_SCOPE_AGENT);
    }

    if (tid < 128) {
        out[OUT_HF + (size_t)ub * HH + j0 + uj] = h_reg;
        out[OUT_CF + (size_t)ub * HH + j0 + uj] = c_reg;
    }
}

extern "C" void kernel_launch(void* const* d_in, const int* in_sizes, int n_in,
                              void* d_out, int out_size, void* d_ws, size_t ws_size,
                              hipStream_t stream) {
    const float* x      = (const float*)d_in[0];
    const float* init_h = (const float*)d_in[1];
    const float* init_c = (const float*)d_in[2];
    const float* Wx     = (const float*)d_in[3];
    const float* Wr     = (const float*)d_in[4];
    const float* bias   = (const float*)d_in[5];
    const int*   mask   = (const int*)d_in[6];
    float* out  = (float*)d_out;

    float*    WT    = (float*)d_ws;                     // 8 MB
    float*    hbuf  = WT + (size_t)GG * KK;             // 256 KB
    unsigned* flags = (unsigned*)(hbuf + 2 * BB * HH);  // 1 KB

    prep_kernel<<<(GG * KK + 255) / 256, 256, 0, stream>>>(Wx, Wr, init_h, WT,
                                                           hbuf, flags);

    void* args[] = { (void*)&x, (void*)&WT, (void*)&bias, (void*)&mask,
                     (void*)&init_h, (void*)&init_c, (void*)&hbuf,
                     (void*)&flags, (void*)&out };
    (void)hipLaunchCooperativeKernel((const void*)lstm_kernel, dim3(NBLK),
                                     dim3(NTHR), args,
                                     (unsigned)(SMEM_FLOATS * sizeof(float)),
                                     stream);
}

// Round 5
// 20484.413 us; speedup vs baseline: 3.7107x; 2.5027x over previous
//
#include <hip/hip_runtime.h>

constexpr int BB = 64, TT = 512, DD = 512, HH = 512;
constexpr int GG = 4 * HH;         // 2048 gate cols
constexpr int NBLK = 256, NTHR = 512;
// LDS: h[64][512] f32 (128KB) + z[64][9] (2.25KB) + mask bits 64*16 u32 (4KB)
constexpr int LDS_BYTES = BB * HH * 4 + 64 * 9 * 4 + 64 * 16 * 4;

// ws: WxT[GG][512] (4MB) | WrT[GG][512] k-permuted (4MB) | hbuf[2][B*H] (256KB)
//     | flags[NBLK] (1KB) | mpack[64][16] u32 (4KB)

__global__ void prep_kernel(const float* __restrict__ Wx,   // [DD][GG]
                            const float* __restrict__ Wr,   // [HH][GG]
                            const float* __restrict__ init_h,
                            const int*   __restrict__ mask, // [B,T]
                            float* __restrict__ WxT,
                            float* __restrict__ WrT,
                            float* __restrict__ hbuf0,
                            unsigned* __restrict__ flags,
                            unsigned* __restrict__ mpack) {
    int idx = blockIdx.x * blockDim.x + threadIdx.x;
    if (idx < GG * 512) {
        int g = idx >> 9;
        int p = idx & 511;
        WxT[idx] = Wx[(size_t)p * GG + g];            // natural k order
        int kg = p >> 4, j = (p >> 2) & 3, c = p & 3; // permuted for LDS reads
        int k  = 4 * kg + 128 * j + c;
        WrT[idx] = Wr[(size_t)k * GG + g];
    }
    if (idx < BB * HH) hbuf0[idx] = init_h[idx];
    if (idx < NBLK) flags[idx] = 0u;
    if (idx < 64 * 16) {            // pack mask bits: word (b,w), bit = t&31
        int b = idx >> 4, w = idx & 15;
        unsigned word = 0u;
        for (int tb = 0; tb < 32; ++tb)
            word |= (mask[b * TT + w * 32 + tb] != 0 ? 1u : 0u) << tb;
        mpack[idx] = word;
    }
}

__device__ __forceinline__ float dot16(float4 a0, float4 a1, float4 a2, float4 a3,
                                       float4 w0, float4 w1, float4 w2, float4 w3) {
    float s0 = 0.f, s1 = 0.f, s2 = 0.f, s3 = 0.f;
    s0 = fmaf(a0.x, w0.x, s0); s1 = fmaf(a0.y, w0.y, s1);
    s2 = fmaf(a0.z, w0.z, s2); s3 = fmaf(a0.w, w0.w, s3);
    s0 = fmaf(a1.x, w1.x, s0); s1 = fmaf(a1.y, w1.y, s1);
    s2 = fmaf(a1.z, w1.z, s2); s3 = fmaf(a1.w, w1.w, s3);
    s0 = fmaf(a2.x, w2.x, s0); s1 = fmaf(a2.y, w2.y, s1);
    s2 = fmaf(a2.z, w2.z, s2); s3 = fmaf(a2.w, w2.w, s3);
    s0 = fmaf(a3.x, w3.x, s0); s1 = fmaf(a3.y, w3.y, s1);
    s2 = fmaf(a3.z, w3.z, s2); s3 = fmaf(a3.w, w3.w, s3);
    return (s0 + s1) + (s2 + s3);
}

__global__ void __launch_bounds__(NTHR, 2)
lstm_kernel(const float* __restrict__ x,      // [B,T,D]
            const float* __restrict__ WxT,    // [GG][512] natural k
            const float* __restrict__ WrT,    // [GG][512] k-permuted
            const float* __restrict__ bias,   // [GG]
            float*       hbuf,                // [2][B*H], sc1-only
            unsigned*    flags,               // [NBLK], sc1-only
            const unsigned* __restrict__ mpack, // [64][16]
            const float* __restrict__ init_h,
            const float* __restrict__ init_c,
            float* __restrict__ out)          // outputs | h_f | c_f
{
    extern __shared__ float smem[];
    float*    h_lds = smem;                        // [64][512]
    float*    z_l   = smem + BB * HH;              // [64][9]
    unsigned* m_lds = (unsigned*)(z_l + 64 * 9);   // [64][16]

    const int tid  = threadIdx.x;
    const int bid  = blockIdx.x;
    const int slot = tid >> 6;           // 0..7 (wave id): gate-col slot
    const int l6   = tid & 63;
    const int bl   = l6 >> 5;            // 0/1 batch parity
    const int kg   = l6 & 31;            // k-group
    const int gate = slot >> 1;
    const int jj   = slot & 1;
    // XCD-friendly column relabeling (bid%8 = XCD under round-robin dispatch)
    const int j0   = 2 * ((bid & 7) * 32 + (bid >> 3));
    const int g    = gate * HH + j0 + jj;

    // ---- persistent weights: 16+16 f32 in VGPRs ----
    const float4* wxr = reinterpret_cast<const float4*>(WxT + (size_t)g * 512);
    const float4* whr = reinterpret_cast<const float4*>(WrT + (size_t)g * 512);
    const int k4 = kg * 4;
    const float4 wx0 = wxr[k4 + 0], wx1 = wxr[k4 + 1],
                 wx2 = wxr[k4 + 2], wx3 = wxr[k4 + 3];
    const float4 wh0 = whr[k4 + 0], wh1 = whr[k4 + 1],
                 wh2 = whr[k4 + 2], wh3 = whr[k4 + 3];
    const float bz = bias[g];

    // ---- update-phase mapping (tid < 128) ----
    const int ub = tid >> 1;
    const int uj = tid & 1;
    float c_reg = 0.f, h_reg = 0.f, po_reg = 0.f;
    if (tid < 128) {
        c_reg = init_c[ub * HH + j0 + uj];
        h_reg = init_h[ub * HH + j0 + uj];
    }

    // mask bits -> LDS once
    for (int i = tid; i < 64 * 16; i += NTHR) m_lds[i] = mpack[i];

    const size_t OUT_HF = (size_t)BB * TT * HH;
    const size_t OUT_CF = OUT_HF + (size_t)BB * HH;
    const int stage_base = slot * 4096 + l6;

    for (int t = 0; t < TT; ++t) {
        // ---- x-phase: one xz value kept per lane (no array -> no spills) ----
        float xs = 0.f;
        #pragma unroll
        for (int it = 0; it < 32; ++it) {
            const float4* xa = reinterpret_cast<const float4*>(
                x + ((size_t)(2 * it + bl) * TT + t) * DD + kg * 16);
            float s = dot16(xa[0], xa[1], xa[2], xa[3], wx0, wx1, wx2, wx3);
            s += __shfl_xor(s, 1);
            s += __shfl_xor(s, 2);
            s += __shfl_xor(s, 4);
            s += __shfl_xor(s, 8);
            s += __shfl_xor(s, 16);
            if (kg == it) xs = s + bz;   // lane kg holds xz(b=2*kg+bl, g)
        }

        // ---- wait: all flags >= t (throttled poll, distinct addrs) ----
        if (tid < 64) {
            const unsigned tgt = (unsigned)t;
            for (;;) {
                bool ok = true;
                #pragma unroll
                for (int q = 0; q < 4; ++q) {
                    unsigned v = __hip_atomic_load(flags + q * 64 + tid,
                                                   __ATOMIC_RELAXED,
                                                   __HIP_MEMORY_SCOPE_AGENT);
                    ok &= (v >= tgt);
                }
                if (__all(ok)) break;
                __builtin_amdgcn_s_sleep(8);
            }
        }
        __syncthreads();

        const float* cur = hbuf + (size_t)(t & 1) * (BB * HH);
        float*       nxt = hbuf + (size_t)((t + 1) & 1) * (BB * HH);

        // ---- stage h -> LDS (sc1 L2-bypass loads, conflict-free ds_write) ----
        #pragma unroll 8
        for (int i = 0; i < 64; ++i) {
            int e = stage_base + i * 64;
            h_lds[e] = __hip_atomic_load(cur + e, __ATOMIC_RELAXED,
                                         __HIP_MEMORY_SCOPE_AGENT);
        }
        __syncthreads();

        // ---- h-phase from LDS (k-permuted) + reduce + z assembly ----
        #pragma unroll
        for (int it = 0; it < 32; ++it) {
            const int b = 2 * it + bl;
            const float4* hrow = reinterpret_cast<const float4*>(h_lds + b * HH);
            float4 h0 = hrow[kg], h1 = hrow[kg + 32],
                   h2 = hrow[kg + 64], h3 = hrow[kg + 96];
            float s = dot16(h0, h1, h2, h3, wh0, wh1, wh2, wh3);
            s += __shfl_xor(s, 1);
            s += __shfl_xor(s, 2);
            s += __shfl_xor(s, 4);
            s += __shfl_xor(s, 8);
            s += __shfl_xor(s, 16);
            float xzv = __shfl(xs, (l6 & 32) | it);   // from lane (bl, kg=it)
            if (kg == 0) z_l[b * 9 + slot] = xzv + s;
        }
        __syncthreads();

        // ---- gates + state update (Keras order i,f,g,o) ----
        if (tid < 128) {
            float zi = z_l[ub * 9 + 0 + uj];
            float zf = z_l[ub * 9 + 2 + uj];
            float zg = z_l[ub * 9 + 4 + uj];
            float zo = z_l[ub * 9 + 6 + uj];

            float ig = 1.f / (1.f + expf(-zi));
            float fg = 1.f / (1.f + expf(-zf));
            float gg = tanhf(zg);
            float og = 1.f / (1.f + expf(-zo));

            float c_new = fg * c_reg + ig * gg;
            float h_new = og * tanhf(c_new);

            bool m = ((m_lds[ub * 16 + (t >> 5)] >> (t & 31)) & 1u) != 0u;
            float ov = m ? h_new : po_reg;
            float h2 = m ? h_new : h_reg;
            float c2 = m ? c_new : c_reg;

            out[((size_t)ub * TT + t) * HH + j0 + uj] = ov;     // cached store
            __hip_atomic_store(nxt + ub * HH + j0 + uj, h2,     // sc1 store
                               __ATOMIC_RELAXED, __HIP_MEMORY_SCOPE_AGENT);

            c_reg = c2; h_reg = h2; po_reg = ov;
        }
        // __syncthreads drains vmcnt -> h sc1-stores reach coherence point
        // before the flag store below issues. No fences needed.
        __syncthreads();

        if (tid == 0)
            __hip_atomic_store(flags + bid, (unsigned)(t + 1),
                               __ATOMIC_RELAXED, __HIP_MEMORY_SCOPE_AGENT);
    }

    if (tid < 128) {
        out[OUT_HF + (size_t)ub * HH + j0 + uj] = h_reg;
        out[OUT_CF + (size_t)ub * HH + j0 + uj] = c_reg;
    }
}

extern "C" void kernel_launch(void* const* d_in, const int* in_sizes, int n_in,
                              void* d_out, int out_size, void* d_ws, size_t ws_size,
                              hipStream_t stream) {
    const float* x      = (const float*)d_in[0];
    const float* init_h = (const float*)d_in[1];
    const float* init_c = (const float*)d_in[2];
    const float* Wx     = (const float*)d_in[3];
    const float* Wr     = (const float*)d_in[4];
    const float* bias   = (const float*)d_in[5];
    const int*   mask   = (const int*)d_in[6];
    float* out  = (float*)d_out;

    float*    WxT   = (float*)d_ws;                      // 4 MB
    float*    WrT   = WxT + (size_t)GG * 512;            // 4 MB
    float*    hbuf  = WrT + (size_t)GG * 512;            // 256 KB
    unsigned* flags = (unsigned*)(hbuf + 2 * BB * HH);   // 1 KB
    unsigned* mpack = flags + NBLK;                      // 4 KB

    prep_kernel<<<(GG * 512 + 255) / 256, 256, 0, stream>>>(
        Wx, Wr, init_h, mask, WxT, WrT, hbuf, flags, mpack);

    void* args[] = { (void*)&x, (void*)&WxT, (void*)&WrT, (void*)&bias,
                     (void*)&hbuf, (void*)&flags, (void*)&mpack,
                     (void*)&init_h, (void*)&init_c, (void*)&out };
    (void)hipLaunchCooperativeKernel((const void*)lstm_kernel, dim3(NBLK),
                                     dim3(NTHR), args, (unsigned)LDS_BYTES,
                                     stream);
}

// Round 6
// 2816.582 us; speedup vs baseline: 26.9870x; 7.2728x over previous
//
#include <hip/hip_runtime.h>

constexpr int BB = 64, TT = 512, DD = 512, HH = 512;
constexpr int GG = 4 * HH;          // 2048 gate cols
constexpr int KK = DD + HH;         // 1024 fused K
constexpr int NBLK = 256, NTHR = 512;
// LDS: A[32][1024] bf16 swizzled (64KB) | zl[8][16][16] f32 (8KB) | mpack (4KB)
constexpr int LDS_BYTES = 32 * 2048 + 8 * 256 * 4 + 64 * 16 * 4;

using short8 = __attribute__((ext_vector_type(8))) short;
using f32x4  = __attribute__((ext_vector_type(4))) float;

__device__ __host__ __forceinline__ unsigned short f2bf(float f) {
    union { float f; unsigned u; } v; v.f = f;
    unsigned u = v.u + 0x7fffu + ((v.u >> 16) & 1u);   // RNE
    return (unsigned short)(u >> 16);
}

// ws: WB[2048][1024] bf16 (4MB) | hbuf[2][BB*HH/2] u32-bf16pairs (128KB)
//     | flags[NBLK] (1KB) | mpack[64][16] (4KB)

__global__ void prep_kernel(const float* __restrict__ Wx,   // [DD][GG]
                            const float* __restrict__ Wr,   // [HH][GG]
                            const float* __restrict__ init_h,
                            const int*   __restrict__ mask, // [B,T]
                            unsigned short* __restrict__ WB,
                            unsigned* __restrict__ hbuf0,
                            unsigned* __restrict__ flags,
                            unsigned* __restrict__ mpack) {
    int idx = blockIdx.x * blockDim.x + threadIdx.x;
    if (idx < GG * KK) {                 // WB[g][k] = W[k][g], bf16
        int g = idx >> 10, k = idx & 1023;
        float v = (k < DD) ? Wx[(size_t)k * GG + g]
                           : Wr[(size_t)(k - DD) * GG + g];
        WB[idx] = f2bf(v);
    }
    if (idx < BB * HH / 2) {             // h0 as packed bf16 pairs
        unsigned lo = f2bf(init_h[2 * idx]);
        unsigned hi = f2bf(init_h[2 * idx + 1]);
        hbuf0[idx] = lo | (hi << 16);
    }
    if (idx < NBLK) flags[idx] = 0u;
    if (idx < 64 * 16) {
        int b = idx >> 4, w = idx & 15;
        unsigned word = 0u;
        for (int tb = 0; tb < 32; ++tb)
            word |= (mask[b * TT + w * 32 + tb] != 0 ? 1u : 0u) << tb;
        mpack[idx] = word;
    }
}

__global__ void __launch_bounds__(NTHR, 1)
lstm_kernel(const float* __restrict__ x,          // [B,T,D]
            const unsigned short* __restrict__ WB,// [2048][1024] bf16
            const float* __restrict__ bias,       // [GG]
            unsigned*    hbuf,                    // [2][B*H/2] u32, sc1-only
            unsigned*    flags,                   // [NBLK], sc1-only
            const unsigned* __restrict__ mpack,   // [64][16]
            const float* __restrict__ init_h,
            const float* __restrict__ init_c,
            float* __restrict__ out)              // outputs | h_f | c_f
{
    extern __shared__ char smem[];                // A: [32 rows][2048B] swizzled
    float*    zl    = (float*)(smem + 32 * 2048); // [8][16][16]
    unsigned* m_lds = (unsigned*)(smem + 32 * 2048 + 8 * 256 * 4);

    const int tid = threadIdx.x;
    const int bid = blockIdx.x;
    const int w   = tid >> 6;          // wave 0..7
    const int l   = tid & 63;
    const int bt  = w & 1;             // b-tile (16 rows) within the 32
    const int ws  = w >> 1;            // k-quarter 0..3
    // block decode: XCD-contiguous j quads
    const int bh     = (bid >> 3) & 1;                 // b-half
    const int qid    = (bid & 7) * 16 + (bid >> 4);    // j-quad 0..127
    const int j_base = qid * 4;

    // ---- persistent B-fragments: W[k][g] for 8 ktiles, 16 g-cols ----
    const int n = l & 15;
    const int g = (n >> 2) * 512 + j_base + (n & 3);   // col n -> global gate
    short8 bf[8];
    {
        const unsigned short* wrow = WB + (size_t)g * KK + (l >> 4) * 8;
        #pragma unroll
        for (int i = 0; i < 8; ++i) {
            int kt = (i < 4) ? (ws * 4 + i) : (16 + ws * 4 + (i - 4));
            bf[i] = *(const short8*)(wrow + kt * 32);
        }
    }

    // ---- update-thread state (tid < 64): (b=tid>>1, j-pair=tid&1) ----
    const int ub = tid >> 1, jp = tid & 1;
    const int b_glob = bh * 32 + ub;
    const int jg0 = j_base + jp * 2;                   // first of 2 j cols
    float c_reg[2] = {0.f, 0.f}, h_reg[2] = {0.f, 0.f}, po_reg[2] = {0.f, 0.f};
    float bias_r[2][4];
    if (tid < 64) {
        #pragma unroll
        for (int jo = 0; jo < 2; ++jo) {
            c_reg[jo] = init_c[b_glob * HH + jg0 + jo];
            h_reg[jo] = init_h[b_glob * HH + jg0 + jo];
            #pragma unroll
            for (int gt = 0; gt < 4; ++gt)
                bias_r[jo][gt] = bias[gt * 512 + jg0 + jo];
        }
    }
    for (int i = tid; i < 64 * 16; i += NTHR) m_lds[i] = mpack[i];

    const size_t OUT_HF = (size_t)BB * TT * HH;
    const size_t OUT_CF = OUT_HF + (size_t)BB * HH;
    const int arow = bt * 16 + (l & 15);               // A row this lane reads
    const int rsw  = (arow & 7) << 4;                  // row XOR swizzle

    for (int t = 0; t < TT; ++t) {
        // ---- stage x[t] (no h dep): wave w stages rows 4w..4w+3 ----
        #pragma unroll
        for (int i = 0; i < 4; ++i) {
            int row = 4 * w + i;
            const float4* xp = (const float4*)(
                x + ((size_t)(bh * 32 + row) * TT + t) * DD + 8 * l);
            float4 f0 = xp[0], f1 = xp[1];
            short8 v;
            v[0] = (short)f2bf(f0.x); v[1] = (short)f2bf(f0.y);
            v[2] = (short)f2bf(f0.z); v[3] = (short)f2bf(f0.w);
            v[4] = (short)f2bf(f1.x); v[5] = (short)f2bf(f1.y);
            v[6] = (short)f2bf(f1.z); v[7] = (short)f2bf(f1.w);
            *(short8*)(smem + row * 2048 + ((16 * l) ^ ((row & 7) << 4))) = v;
        }
        __syncthreads();

        // ---- x-MFMAs (kt = ws*4 .. +3), accumulate in regs ----
        f32x4 acc = {0.f, 0.f, 0.f, 0.f};
        #pragma unroll
        for (int i = 0; i < 4; ++i) {
            int kt = ws * 4 + i;
            short8 a = *(const short8*)(
                smem + arow * 2048 + ((kt * 64 + (l >> 4) * 16) ^ rsw));
            acc = __builtin_amdgcn_mfma_f32_16x16x32_bf16(a, bf[i], acc, 0, 0, 0);
        }

        // ---- wait: all flags >= t ----
        if (w == 0) {
            const unsigned tgt = (unsigned)t;
            for (;;) {
                bool ok = true;
                #pragma unroll
                for (int q = 0; q < 4; ++q) {
                    unsigned v = __hip_atomic_load(flags + q * 64 + l,
                                                   __ATOMIC_RELAXED,
                                                   __HIP_MEMORY_SCOPE_AGENT);
                    ok &= (v >= tgt);
                }
                if (__all(ok)) break;
                __builtin_amdgcn_s_sleep(8);
            }
        }
        __syncthreads();

        // ---- stage h (bf16 pairs from LLC, straight into LDS) ----
        const unsigned* curb = hbuf + (size_t)(t & 1) * (BB * HH / 2);
        #pragma unroll
        for (int i = 0; i < 4; ++i) {
            int row = 4 * w + i;
            const unsigned* hp = curb + (size_t)(bh * 32 + row) * 256 + 4 * l;
            unsigned u0 = __hip_atomic_load(hp + 0, __ATOMIC_RELAXED,
                                            __HIP_MEMORY_SCOPE_AGENT);
            unsigned u1 = __hip_atomic_load(hp + 1, __ATOMIC_RELAXED,
                                            __HIP_MEMORY_SCOPE_AGENT);
            unsigned u2 = __hip_atomic_load(hp + 2, __ATOMIC_RELAXED,
                                            __HIP_MEMORY_SCOPE_AGENT);
            unsigned u3 = __hip_atomic_load(hp + 3, __ATOMIC_RELAXED,
                                            __HIP_MEMORY_SCOPE_AGENT);
            uint4 hu = make_uint4(u0, u1, u2, u3);
            short8 hv = *reinterpret_cast<short8*>(&hu);
            *(short8*)(smem + row * 2048 +
                       ((1024 + 16 * l) ^ ((row & 7) << 4))) = hv;
        }
        __syncthreads();

        // ---- h-MFMAs (kt = 16 + ws*4 .. +3), write partials ----
        #pragma unroll
        for (int i = 0; i < 4; ++i) {
            int kt = 16 + ws * 4 + i;
            short8 a = *(const short8*)(
                smem + arow * 2048 + ((kt * 64 + (l >> 4) * 16) ^ rsw));
            acc = __builtin_amdgcn_mfma_f32_16x16x32_bf16(a, bf[4 + i], acc, 0, 0, 0);
        }
        #pragma unroll
        for (int r = 0; r < 4; ++r)
            zl[(w * 16 + (l >> 4) * 4 + r) * 16 + (l & 15)] = acc[r];
        __syncthreads();

        // ---- update (64 threads): sum 4 k-partials, gates, stores ----
        unsigned* nxtb = hbuf + (size_t)((t + 1) & 1) * (BB * HH / 2);
        if (tid < 64) {
            const int btu = ub >> 4, m = ub & 15;
            float ov[2], h2[2];
            bool msk = ((m_lds[b_glob * 16 + (t >> 5)] >> (t & 31)) & 1u) != 0u;
            #pragma unroll
            for (int jo = 0; jo < 2; ++jo) {
                int jj = jp * 2 + jo;
                float z[4];
                #pragma unroll
                for (int gt = 0; gt < 4; ++gt) {
                    float s = bias_r[jo][gt];
                    #pragma unroll
                    for (int p = 0; p < 4; ++p)
                        s += zl[((p * 2 + btu) * 16 + m) * 16 + gt * 4 + jj];
                    z[gt] = s;
                }
                float ig = 1.f / (1.f + expf(-z[0]));
                float fg = 1.f / (1.f + expf(-z[1]));
                float gg = tanhf(z[2]);
                float og = 1.f / (1.f + expf(-z[3]));
                float c_new = fg * c_reg[jo] + ig * gg;
                float h_new = og * tanhf(c_new);
                ov[jo] = msk ? h_new : po_reg[jo];
                h2[jo] = msk ? h_new : h_reg[jo];
                float c2 = msk ? c_new : c_reg[jo];
                c_reg[jo] = c2; h_reg[jo] = h2[jo]; po_reg[jo] = ov[jo];
            }
            *(float2*)(out + ((size_t)b_glob * TT + t) * HH + jg0) =
                make_float2(ov[0], ov[1]);
            unsigned hp32 = (unsigned)f2bf(h2[0]) | ((unsigned)f2bf(h2[1]) << 16);
            __hip_atomic_store(nxtb + b_glob * 256 + qid * 2 + jp, hp32,
                               __ATOMIC_RELAXED, __HIP_MEMORY_SCOPE_AGENT);
        }
        // syncthreads drains each wave's stores before s_barrier -> h at
        // coherence point before the flag store below. No fences.
        __syncthreads();

        if (tid == 0)
            __hip_atomic_store(flags + bid, (unsigned)(t + 1),
                               __ATOMIC_RELAXED, __HIP_MEMORY_SCOPE_AGENT);
    }

    if (tid < 64) {
        *(float2*)(out + OUT_HF + (size_t)b_glob * HH + jg0) =
            make_float2(h_reg[0], h_reg[1]);
        *(float2*)(out + OUT_CF + (size_t)b_glob * HH + jg0) =
            make_float2(c_reg[0], c_reg[1]);
    }
}

extern "C" void kernel_launch(void* const* d_in, const int* in_sizes, int n_in,
                              void* d_out, int out_size, void* d_ws, size_t ws_size,
                              hipStream_t stream) {
    const float* x      = (const float*)d_in[0];
    const float* init_h = (const float*)d_in[1];
    const float* init_c = (const float*)d_in[2];
    const float* Wx     = (const float*)d_in[3];
    const float* Wr     = (const float*)d_in[4];
    const float* bias   = (const float*)d_in[5];
    const int*   mask   = (const int*)d_in[6];
    float* out = (float*)d_out;

    unsigned short* WB    = (unsigned short*)d_ws;           // 4 MB
    unsigned*       hbuf  = (unsigned*)(WB + (size_t)GG * KK); // 128 KB
    unsigned*       flags = hbuf + 2 * (BB * HH / 2);        // 1 KB
    unsigned*       mpack = flags + NBLK;                    // 4 KB

    prep_kernel<<<(GG * KK + 255) / 256, 256, 0, stream>>>(
        Wx, Wr, init_h, mask, WB, hbuf, flags, mpack);

    void* args[] = { (void*)&x, (void*)&WB, (void*)&bias, (void*)&hbuf,
                     (void*)&flags, (void*)&mpack, (void*)&init_h,
                     (void*)&init_c, (void*)&out };
    (void)hipLaunchCooperativeKernel((const void*)lstm_kernel, dim3(NBLK),
                                     dim3(NTHR), args, (unsigned)LDS_BYTES,
                                     stream);
}